// Round 1
// baseline (39335.760 us; speedup 1.0000x reference)
//
#include <hip/hip_runtime.h>

// GRU scan: B=32, S=1024, IN=512, H=1024.
// Persistent-kernel design: 64 workgroups x 1 wave, 2 grid barriers per step.
// bf16 MFMA with f32 accumulate; f32 master copy of h for the convex update.

#define B_   32
#define S_   1024
#define IN_  512
#define H_   1024
#define K_   1536
#define NWG  64

typedef __bf16 bf16;
typedef __bf16 bf16x8 __attribute__((ext_vector_type(8)));
typedef float  f32x16 __attribute__((ext_vector_type(16)));
typedef float  f32x4  __attribute__((ext_vector_type(4)));

// ---------------- ws layout (bytes) ----------------
#define OFF_CNT   ((size_t)0)                              // barrier counter (1 KiB reserved)
#define OFF_XB    ((size_t)1024)                           // x bf16: 32*1024*512*2 = 32 MiB
#define OFF_WZR   (OFF_XB  + (size_t)B_*S_*IN_*2)          // [W_z;W_r] bf16: 2048*1536*2 = 6 MiB
#define OFF_WH    (OFF_WZR + (size_t)2*H_*K_*2)            // W_h bf16: 3 MiB
#define OFF_HB0   (OFF_WH  + (size_t)H_*K_*2)              // h bf16 buf0: 64 KiB
#define OFF_HB1   (OFF_HB0 + (size_t)B_*H_*2)              // h bf16 buf1
#define OFF_HF0   (OFF_HB1 + (size_t)B_*H_*2)              // h f32 buf0: 128 KiB
#define OFF_HF1   (OFF_HF0 + (size_t)B_*H_*4)              // h f32 buf1
#define OFF_RH    (OFF_HF1 + (size_t)B_*H_*4)              // (r*h) bf16: 64 KiB
#define OFF_Z     (OFF_RH  + (size_t)B_*H_*2)              // z f32: 128 KiB

__global__ void cvt_f32_bf16(const float* __restrict__ src, bf16* __restrict__ dst, int n4) {
  int i = blockIdx.x * blockDim.x + threadIdx.x;
  if (i >= n4) return;
  float4 v = reinterpret_cast<const float4*>(src)[i];
  union { bf16 b[4]; uint2 u; } o;
  o.b[0] = (bf16)v.x; o.b[1] = (bf16)v.y; o.b[2] = (bf16)v.z; o.b[3] = (bf16)v.w;
  reinterpret_cast<uint2*>(dst)[i] = o.u;
}

__global__ void init_h(const float* __restrict__ ih, float* __restrict__ hf0, bf16* __restrict__ hb0) {
  int i = blockIdx.x * blockDim.x + threadIdx.x;   // 0 .. B_*H_-1
  float v = ih[i & (H_ - 1)];
  hf0[i] = v;
  hb0[i] = (bf16)v;
}

// Grid barrier: monotonic counter, device-scope. One wave per WG, so the
// wave-level waitcnt in __threadfence covers all 64 lanes' stores.
__device__ inline void gbar(int* cnt, int target) {
  __threadfence();                                   // release (L2 wb)
  if (threadIdx.x == 0) {
    __hip_atomic_fetch_add(cnt, 1, __ATOMIC_ACQ_REL, __HIP_MEMORY_SCOPE_AGENT);
    while (__hip_atomic_load(cnt, __ATOMIC_ACQUIRE, __HIP_MEMORY_SCOPE_AGENT) < target)
      __builtin_amdgcn_s_sleep(1);
  }
  __syncthreads();
  __threadfence();                                   // acquire (cache inv)
}

__device__ inline float sigmoid_f(float x) { return 1.f / (1.f + __expf(-x)); }
__device__ inline float tanh_f(float x) {
  x = fminf(20.f, fmaxf(-20.f, x));
  float e = __expf(-2.f * x);
  return (1.f - e) / (1.f + e);
}

__global__ void __launch_bounds__(64) gru_persist(
    const bf16* __restrict__ xb, const bf16* __restrict__ wzr, const bf16* __restrict__ wh,
    const float* __restrict__ bz, const float* __restrict__ br, const float* __restrict__ bh,
    bf16* __restrict__ hb0, bf16* __restrict__ hb1,
    float* __restrict__ hf0, float* __restrict__ hf1,
    bf16* __restrict__ rhb, float* __restrict__ zbuf,
    float* __restrict__ out, int* cnt)
{
  const int w    = blockIdx.x;
  const int l    = threadIdx.x;
  const int lo   = l & 31, hi   = l >> 5;   // 32x32 tile coords
  const int lo16 = l & 15, hi16 = l >> 4;   // 16x16 tile coords
  int bar = 1;

  // Phase A: WG w owns cols [32w, 32w+32) of the [z | r] (N=2048) output.
  const int  nA  = w * 32 + lo;
  const bool isZ = (w < 32);
  const int  cA  = isZ ? nA : nA - H_;
  const float biasA = isZ ? bz[cA] : br[cA];
  const bf16* wA = wzr + (size_t)nA * K_ + hi * 8;

  // Phase B: WG w owns cols [16w, 16w+16) of h.
  const int  cB = w * 16 + lo16;
  const float biasB = bh[cB];
  const bf16* wB = wh + (size_t)cB * K_ + hi16 * 8;

  for (int t = 0; t < S_; ++t) {
    const bf16*  hbp = (t & 1) ? hb1 : hb0;
    const float* hfp = (t & 1) ? hf1 : hf0;
    bf16*  hbn = (t & 1) ? hb0 : hb1;
    float* hfn = (t & 1) ? hf0 : hf1;

    // ---------------- phase A: z,r = sigmoid([x_t,h] @ Wzr^T + b) ----------------
    f32x16 aX, aH0, aH1;
    #pragma unroll
    for (int i = 0; i < 16; ++i) { aX[i] = 0.f; aH0[i] = 0.f; aH1[i] = 0.f; }
    {
      const bf16* pa = xb + ((size_t)lo * S_ + t) * IN_ + hi * 8;
      #pragma unroll 4
      for (int kk = 0; kk < IN_ / 16; ++kk) {              // K 0..511 (x part)
        bf16x8 av = *reinterpret_cast<const bf16x8*>(pa + kk * 16);
        bf16x8 bv = *reinterpret_cast<const bf16x8*>(wA + kk * 16);
        aX = __builtin_amdgcn_mfma_f32_32x32x16_bf16(av, bv, aX, 0, 0, 0);
      }
      const bf16* ph  = hbp + lo * H_ + hi * 8;
      const bf16* wA2 = wA + IN_;
      #pragma unroll 4
      for (int kk = 0; kk < 32; ++kk) {                    // K 512..1023 (h part lo)
        bf16x8 av = *reinterpret_cast<const bf16x8*>(ph + kk * 16);
        bf16x8 bv = *reinterpret_cast<const bf16x8*>(wA2 + kk * 16);
        aH0 = __builtin_amdgcn_mfma_f32_32x32x16_bf16(av, bv, aH0, 0, 0, 0);
      }
      const bf16* ph2 = ph + H_ / 2;
      const bf16* wA3 = wA2 + H_ / 2;
      #pragma unroll 4
      for (int kk = 0; kk < 32; ++kk) {                    // K 1024..1535 (h part hi)
        bf16x8 av = *reinterpret_cast<const bf16x8*>(ph2 + kk * 16);
        bf16x8 bv = *reinterpret_cast<const bf16x8*>(wA3 + kk * 16);
        aH1 = __builtin_amdgcn_mfma_f32_32x32x16_bf16(av, bv, aH1, 0, 0, 0);
      }
    }
    // D layout (verified): col = lane&31, row = (reg&3) + 8*(reg>>2) + 4*(lane>>5)
    if (isZ) {
      #pragma unroll
      for (int rg = 0; rg < 16; ++rg) {
        int m = (rg & 3) + 8 * (rg >> 2) + 4 * hi;
        float v = aX[rg] + aH0[rg] + aH1[rg] + biasA;
        zbuf[m * H_ + cA] = sigmoid_f(v);
      }
    } else {
      #pragma unroll
      for (int rg = 0; rg < 16; ++rg) {
        int m = (rg & 3) + 8 * (rg >> 2) + 4 * hi;
        float v = aX[rg] + aH0[rg] + aH1[rg] + biasA;
        float r = sigmoid_f(v);
        rhb[m * H_ + cA] = (bf16)(r * hfp[m * H_ + cA]);
      }
    }
    gbar(cnt, (bar++) * NWG);

    // ---------------- phase B: h' = (1-z)h + z*tanh([x_t, r*h] @ Wh^T + b) ----------------
    f32x4 a0x, a0h, a1x, a1h;
    #pragma unroll
    for (int i = 0; i < 4; ++i) { a0x[i] = 0.f; a0h[i] = 0.f; a1x[i] = 0.f; a1h[i] = 0.f; }
    {
      const bf16* pa0 = xb + ((size_t)lo16 * S_ + t) * IN_ + hi16 * 8;
      const bf16* pa1 = xb + ((size_t)(lo16 + 16) * S_ + t) * IN_ + hi16 * 8;
      #pragma unroll 4
      for (int kk = 0; kk < IN_ / 32; ++kk) {              // x part
        bf16x8 bv = *reinterpret_cast<const bf16x8*>(wB + kk * 32);
        bf16x8 a0 = *reinterpret_cast<const bf16x8*>(pa0 + kk * 32);
        bf16x8 a1 = *reinterpret_cast<const bf16x8*>(pa1 + kk * 32);
        a0x = __builtin_amdgcn_mfma_f32_16x16x32_bf16(a0, bv, a0x, 0, 0, 0);
        a1x = __builtin_amdgcn_mfma_f32_16x16x32_bf16(a1, bv, a1x, 0, 0, 0);
      }
      const bf16* wB2 = wB + IN_;
      const bf16* ph0 = rhb + lo16 * H_ + hi16 * 8;
      const bf16* ph1 = rhb + (lo16 + 16) * H_ + hi16 * 8;
      #pragma unroll 4
      for (int kk = 0; kk < H_ / 32; ++kk) {               // (r*h) part
        bf16x8 bv = *reinterpret_cast<const bf16x8*>(wB2 + kk * 32);
        bf16x8 a0 = *reinterpret_cast<const bf16x8*>(ph0 + kk * 32);
        bf16x8 a1 = *reinterpret_cast<const bf16x8*>(ph1 + kk * 32);
        a0h = __builtin_amdgcn_mfma_f32_16x16x32_bf16(a0, bv, a0h, 0, 0, 0);
        a1h = __builtin_amdgcn_mfma_f32_16x16x32_bf16(a1, bv, a1h, 0, 0, 0);
      }
    }
    // D layout (verified): col = lane&15, row = (lane>>4)*4 + reg
    #pragma unroll
    for (int tt = 0; tt < 2; ++tt) {
      #pragma unroll
      for (int rg = 0; rg < 4; ++rg) {
        int m = tt * 16 + hi16 * 4 + rg;
        float pre = (tt ? (a1x[rg] + a1h[rg]) : (a0x[rg] + a0h[rg])) + biasB;
        float hh = tanh_f(pre);
        float hp = hfp[m * H_ + cB];
        float z  = zbuf[m * H_ + cB];
        float hn = (1.f - z) * hp + z * hh;
        hfn[m * H_ + cB] = hn;
        hbn[m * H_ + cB] = (bf16)hn;
        out[((size_t)m * S_ + t) * H_ + cB] = hn;
        if (t == S_ - 1) out[(size_t)B_ * S_ * H_ + m * H_ + cB] = hn;
      }
    }
    if (t + 1 < S_) gbar(cnt, (bar++) * NWG);
  }
}

extern "C" void kernel_launch(void* const* d_in, const int* in_sizes, int n_in,
                              void* d_out, int out_size, void* d_ws, size_t ws_size,
                              hipStream_t stream) {
  (void)in_sizes; (void)n_in; (void)out_size; (void)ws_size;
  const float* x  = (const float*)d_in[0];
  const float* Wz = (const float*)d_in[1];
  const float* bz = (const float*)d_in[2];
  const float* Wr = (const float*)d_in[3];
  const float* br = (const float*)d_in[4];
  const float* Wh = (const float*)d_in[5];
  const float* bh = (const float*)d_in[6];
  const float* ih = (const float*)d_in[7];
  float* out = (float*)d_out;
  char*  ws  = (char*)d_ws;

  bf16*  xb   = (bf16*)(ws + OFF_XB);
  bf16*  wzr  = (bf16*)(ws + OFF_WZR);
  bf16*  wh   = (bf16*)(ws + OFF_WH);
  bf16*  hb0  = (bf16*)(ws + OFF_HB0);
  bf16*  hb1  = (bf16*)(ws + OFF_HB1);
  float* hf0  = (float*)(ws + OFF_HF0);
  float* hf1  = (float*)(ws + OFF_HF1);
  bf16*  rhb  = (bf16*)(ws + OFF_RH);
  float* zbuf = (float*)(ws + OFF_Z);
  int*   cnt  = (int*)(ws + OFF_CNT);

  hipMemsetAsync(ws + OFF_CNT, 0, 1024, stream);

  const int n4x = B_ * S_ * IN_ / 4;                       // 4,194,304
  cvt_f32_bf16<<<n4x / 256, 256, 0, stream>>>(x, xb, n4x);
  const int n4w = H_ * K_ / 4;                             // 393,216
  cvt_f32_bf16<<<n4w / 256, 256, 0, stream>>>(Wz, wzr, n4w);
  cvt_f32_bf16<<<n4w / 256, 256, 0, stream>>>(Wr, wzr + (size_t)H_ * K_, n4w);
  cvt_f32_bf16<<<n4w / 256, 256, 0, stream>>>(Wh, wh, n4w);
  init_h<<<(B_ * H_) / 256, 256, 0, stream>>>(ih, hf0, hb0);

  gru_persist<<<NWG, 64, 0, stream>>>(xb, wzr, wh, bz, br, bh,
                                      hb0, hb1, hf0, hf1, rhb, zbuf, out, cnt);
}

// Round 2
// 28301.996 us; speedup vs baseline: 1.3899x; 1.3899x over previous
//
#include <hip/hip_runtime.h>

// GRU scan: B=32, S=1024, IN=512, H=1024.
// Persistent kernel, 64 WGs x 1 wave, 2 grid barriers/step.
// R2: per-WG weight slices staged in LDS (144.5 KB, padded strides -> <=2-way
// bank aliasing, free); relaxed-spin barrier with single acquire fence;
// master h kept in registers (f32) by its owning WG.

#define B_   32
#define S_   1024
#define IN_  512
#define H_   1024
#define K_   1536
#define NWG  64

typedef __bf16 bf16;
typedef __bf16 bf16x8 __attribute__((ext_vector_type(8)));
typedef float  f32x16 __attribute__((ext_vector_type(16)));
typedef float  f32x4  __attribute__((ext_vector_type(4)));

// ---------------- ws layout (bytes) ----------------
#define OFF_CNT ((size_t)0)                       // barrier counter (1 KiB)
#define OFF_XB  ((size_t)1024)                    // x bf16: 32 MiB
#define OFF_WZR (OFF_XB  + (size_t)B_*S_*IN_*2)   // [W_z;W_r] bf16: 6 MiB
#define OFF_WH  (OFF_WZR + (size_t)2*H_*K_*2)     // W_h bf16: 3 MiB
#define OFF_HB  (OFF_WH  + (size_t)H_*K_*2)       // h bf16: 64 KiB (single buffer)
#define OFF_RH  (OFF_HB  + (size_t)B_*H_*2)       // (r*h) bf16: 64 KiB
#define OFF_Z   (OFF_RH  + (size_t)B_*H_*2)       // z f32: 128 KiB

// ---------------- LDS layout ----------------
// Phase A slice: 32 cols x 1536 bf16, col stride 3088 B (3072+16 pad -> slot=col+grp mod 32, 2-way)
// Phase B slice: 16 cols x 1536 bf16, col stride 3136 B (3072+64 pad -> slot=4col+grp, 2-way)
#define SA_STRIDE 3088
#define SB_STRIDE 3136
#define LDSB_OFF  (32 * SA_STRIDE)                 // 98816
#define LDS_TOTAL (LDSB_OFF + 16 * SB_STRIDE)      // 148992 <= 163840

__global__ void cvt_f32_bf16(const float* __restrict__ src, bf16* __restrict__ dst, int n4) {
  int i = blockIdx.x * blockDim.x + threadIdx.x;
  if (i >= n4) return;
  float4 v = reinterpret_cast<const float4*>(src)[i];
  union { bf16 b[4]; uint2 u; } o;
  o.b[0] = (bf16)v.x; o.b[1] = (bf16)v.y; o.b[2] = (bf16)v.z; o.b[3] = (bf16)v.w;
  reinterpret_cast<uint2*>(dst)[i] = o.u;
}

__global__ void init_hb(const float* __restrict__ ih, bf16* __restrict__ hb) {
  int i = blockIdx.x * blockDim.x + threadIdx.x;   // 0 .. B_*H_-1
  hb[i] = (bf16)ih[i & (H_ - 1)];
}

// Grid barrier: arrive with ACQ_REL (release = wb of this XCD's L2), spin
// RELAXED (no per-poll invalidate!), one acquire fence on exit.
__device__ inline void gbar(int* cnt, int target) {
  if (threadIdx.x == 0) {
    __hip_atomic_fetch_add(cnt, 1, __ATOMIC_ACQ_REL, __HIP_MEMORY_SCOPE_AGENT);
    while (__hip_atomic_load(cnt, __ATOMIC_RELAXED, __HIP_MEMORY_SCOPE_AGENT) < target)
      __builtin_amdgcn_s_sleep(1);
  }
  __builtin_amdgcn_fence(__ATOMIC_ACQUIRE, "agent");
  __syncthreads();
}

__device__ inline float sigmoid_f(float x) { return 1.f / (1.f + __expf(-x)); }
__device__ inline float tanh_f(float x) {
  x = fminf(20.f, fmaxf(-20.f, x));
  float e = __expf(-2.f * x);
  return (1.f - e) / (1.f + e);
}

__global__ void __launch_bounds__(64, 1) gru_persist(
    const bf16* __restrict__ xb, const bf16* __restrict__ wzr, const bf16* __restrict__ wh,
    const float* __restrict__ bz, const float* __restrict__ br, const float* __restrict__ bh,
    const float* __restrict__ ih,
    bf16* __restrict__ hb, bf16* __restrict__ rhb, float* __restrict__ zbuf,
    float* __restrict__ out, int* cnt)
{
  extern __shared__ char smem[];
  const int w    = blockIdx.x;
  const int l    = threadIdx.x;
  const int lo   = l & 31, hi   = l >> 5;   // 32x32 tile coords
  const int lo16 = l & 15, hi16 = l >> 4;   // 16x16 tile coords

  // ---- one-time: stage this WG's weight slices into LDS (padded strides) ----
  {
    const char* srcA = (const char*)(wzr + (size_t)(w * 32) * K_);
    for (int c = 0; c < 32; ++c)
      for (int ch = 0; ch < 3; ++ch) {
        int off = ch * 1024 + l * 16;
        *(bf16x8*)(smem + c * SA_STRIDE + off) =
            *(const bf16x8*)(srcA + (size_t)c * 3072 + off);
      }
    const char* srcB = (const char*)(wh + (size_t)(w * 16) * K_);
    for (int c = 0; c < 16; ++c)
      for (int ch = 0; ch < 3; ++ch) {
        int off = ch * 1024 + l * 16;
        *(bf16x8*)(smem + LDSB_OFF + c * SB_STRIDE + off) =
            *(const bf16x8*)(srcB + (size_t)c * 3072 + off);
      }
  }
  __syncthreads();

  // Phase A: WG w owns cols [32w, 32w+32) of [z | r] (N=2048).
  const int  nA  = w * 32 + lo;
  const bool isZ = (w < 32);
  const int  cA  = isZ ? nA : nA - H_;
  const float biasA = isZ ? bz[cA] : br[cA];

  // Phase B: WG w owns cols [16w, 16w+16) of h — forever. Master h in regs.
  const int  cB = w * 16 + lo16;
  const float biasB = bh[cB];
  const float ihv = ih[cB];
  f32x4 hown0, hown1;
  #pragma unroll
  for (int rg = 0; rg < 4; ++rg) { hown0[rg] = ihv; hown1[rg] = ihv; }

  const char* bA = smem + lo * SA_STRIDE + hi * 16;
  const char* bB = smem + LDSB_OFF + lo16 * SB_STRIDE + hi16 * 16;

  int target = NWG;
  for (int t = 0; t < S_; ++t) {
    // ---------------- phase A: z,r = sigmoid([x_t,h] @ Wzr^T + b) ----------------
    f32x16 aX, aH0, aH1;
    #pragma unroll
    for (int i = 0; i < 16; ++i) { aX[i] = 0.f; aH0[i] = 0.f; aH1[i] = 0.f; }
    {
      const bf16* pa = xb + ((size_t)lo * S_ + t) * IN_ + hi * 8;
      #pragma unroll 8
      for (int kk = 0; kk < 32; ++kk) {                   // K 0..511 (x)
        bf16x8 av = *reinterpret_cast<const bf16x8*>(pa + kk * 16);
        bf16x8 bv = *reinterpret_cast<const bf16x8*>(bA + kk * 32);
        aX = __builtin_amdgcn_mfma_f32_32x32x16_bf16(av, bv, aX, 0, 0, 0);
      }
      const bf16* ph = hb + lo * H_ + hi * 8;
      #pragma unroll 8
      for (int kk = 0; kk < 32; ++kk) {                   // K 512..1023 (h lo)
        bf16x8 av = *reinterpret_cast<const bf16x8*>(ph + kk * 16);
        bf16x8 bv = *reinterpret_cast<const bf16x8*>(bA + 1024 + kk * 32);
        aH0 = __builtin_amdgcn_mfma_f32_32x32x16_bf16(av, bv, aH0, 0, 0, 0);
      }
      #pragma unroll 8
      for (int kk = 0; kk < 32; ++kk) {                   // K 1024..1535 (h hi)
        bf16x8 av = *reinterpret_cast<const bf16x8*>(ph + 512 + kk * 16);
        bf16x8 bv = *reinterpret_cast<const bf16x8*>(bA + 2048 + kk * 32);
        aH1 = __builtin_amdgcn_mfma_f32_32x32x16_bf16(av, bv, aH1, 0, 0, 0);
      }
    }
    // D layout: col = lane&31, row = (reg&3) + 8*(reg>>2) + 4*(lane>>5)
    if (isZ) {
      #pragma unroll
      for (int rg = 0; rg < 16; ++rg) {
        int m = (rg & 3) + 8 * (rg >> 2) + 4 * hi;
        float v = aX[rg] + aH0[rg] + aH1[rg] + biasA;
        zbuf[m * H_ + cA] = sigmoid_f(v);
      }
    } else {
      #pragma unroll
      for (int rg = 0; rg < 16; ++rg) {
        int m = (rg & 3) + 8 * (rg >> 2) + 4 * hi;
        float v = aX[rg] + aH0[rg] + aH1[rg] + biasA;
        float r = sigmoid_f(v);
        rhb[m * H_ + cA] = (bf16)(r * (float)hb[m * H_ + cA]);
      }
    }
    gbar(cnt, target); target += NWG;

    // ------------- phase B: h' = h + z*(tanh([x_t, r*h] @ Wh^T + b) - h) -------------
    f32x4 a0x, a0h, a1x, a1h;
    #pragma unroll
    for (int i = 0; i < 4; ++i) { a0x[i] = 0.f; a0h[i] = 0.f; a1x[i] = 0.f; a1h[i] = 0.f; }
    {
      const bf16* pa0 = xb + ((size_t)lo16 * S_ + t) * IN_ + hi16 * 8;
      const bf16* pa1 = xb + ((size_t)(lo16 + 16) * S_ + t) * IN_ + hi16 * 8;
      #pragma unroll 8
      for (int kk = 0; kk < 16; ++kk) {                   // x part
        bf16x8 bv = *reinterpret_cast<const bf16x8*>(bB + kk * 64);
        bf16x8 a0 = *reinterpret_cast<const bf16x8*>(pa0 + kk * 32);
        bf16x8 a1 = *reinterpret_cast<const bf16x8*>(pa1 + kk * 32);
        a0x = __builtin_amdgcn_mfma_f32_16x16x32_bf16(a0, bv, a0x, 0, 0, 0);
        a1x = __builtin_amdgcn_mfma_f32_16x16x32_bf16(a1, bv, a1x, 0, 0, 0);
      }
      const bf16* ph0 = rhb + lo16 * H_ + hi16 * 8;
      const bf16* ph1 = rhb + (lo16 + 16) * H_ + hi16 * 8;
      #pragma unroll 8
      for (int kk = 0; kk < 32; ++kk) {                   // (r*h) part
        bf16x8 bv = *reinterpret_cast<const bf16x8*>(bB + 1024 + kk * 64);
        bf16x8 a0 = *reinterpret_cast<const bf16x8*>(ph0 + kk * 32);
        bf16x8 a1 = *reinterpret_cast<const bf16x8*>(ph1 + kk * 32);
        a0h = __builtin_amdgcn_mfma_f32_16x16x32_bf16(a0, bv, a0h, 0, 0, 0);
        a1h = __builtin_amdgcn_mfma_f32_16x16x32_bf16(a1, bv, a1h, 0, 0, 0);
      }
    }
    // D layout: col = lane&15, row = (lane>>4)*4 + reg
    #pragma unroll
    for (int rg = 0; rg < 4; ++rg) {
      int m0 = hi16 * 4 + rg;
      float hh0 = tanh_f(a0x[rg] + a0h[rg] + biasB);
      float z0  = zbuf[m0 * H_ + cB];
      float hn0 = hown0[rg] + z0 * (hh0 - hown0[rg]);
      hown0[rg] = hn0;
      hb[m0 * H_ + cB] = (bf16)hn0;
      out[((size_t)m0 * S_ + t) * H_ + cB] = hn0;

      int m1 = m0 + 16;
      float hh1 = tanh_f(a1x[rg] + a1h[rg] + biasB);
      float z1  = zbuf[m1 * H_ + cB];
      float hn1 = hown1[rg] + z1 * (hh1 - hown1[rg]);
      hown1[rg] = hn1;
      hb[m1 * H_ + cB] = (bf16)hn1;
      out[((size_t)m1 * S_ + t) * H_ + cB] = hn1;
    }
    if (t == S_ - 1) {
      #pragma unroll
      for (int rg = 0; rg < 4; ++rg) {
        int m0 = hi16 * 4 + rg, m1 = m0 + 16;
        out[(size_t)B_ * S_ * H_ + m0 * H_ + cB] = hown0[rg];
        out[(size_t)B_ * S_ * H_ + m1 * H_ + cB] = hown1[rg];
      }
    }
    if (t + 1 < S_) { gbar(cnt, target); target += NWG; }
  }
}

extern "C" void kernel_launch(void* const* d_in, const int* in_sizes, int n_in,
                              void* d_out, int out_size, void* d_ws, size_t ws_size,
                              hipStream_t stream) {
  (void)in_sizes; (void)n_in; (void)out_size; (void)ws_size;
  const float* x  = (const float*)d_in[0];
  const float* Wz = (const float*)d_in[1];
  const float* bz = (const float*)d_in[2];
  const float* Wr = (const float*)d_in[3];
  const float* br = (const float*)d_in[4];
  const float* Wh = (const float*)d_in[5];
  const float* bh = (const float*)d_in[6];
  const float* ih = (const float*)d_in[7];
  float* out = (float*)d_out;
  char*  ws  = (char*)d_ws;

  bf16*  xb   = (bf16*)(ws + OFF_XB);
  bf16*  wzr  = (bf16*)(ws + OFF_WZR);
  bf16*  wh   = (bf16*)(ws + OFF_WH);
  bf16*  hb   = (bf16*)(ws + OFF_HB);
  bf16*  rhb  = (bf16*)(ws + OFF_RH);
  float* zbuf = (float*)(ws + OFF_Z);
  int*   cnt  = (int*)(ws + OFF_CNT);

  hipFuncSetAttribute(reinterpret_cast<const void*>(&gru_persist),
                      hipFuncAttributeMaxDynamicSharedMemorySize, LDS_TOTAL);

  hipMemsetAsync(ws + OFF_CNT, 0, 1024, stream);

  const int n4x = B_ * S_ * IN_ / 4;
  cvt_f32_bf16<<<n4x / 256, 256, 0, stream>>>(x, xb, n4x);
  const int n4w = H_ * K_ / 4;
  cvt_f32_bf16<<<n4w / 256, 256, 0, stream>>>(Wz, wzr, n4w);
  cvt_f32_bf16<<<n4w / 256, 256, 0, stream>>>(Wr, wzr + (size_t)H_ * K_, n4w);
  cvt_f32_bf16<<<n4w / 256, 256, 0, stream>>>(Wh, wh, n4w);
  init_hb<<<(B_ * H_) / 256, 256, 0, stream>>>(ih, hb);

  gru_persist<<<NWG, 64, LDS_TOTAL, stream>>>(xb, wzr, wh, bz, br, bh, ih,
                                              hb, rhb, zbuf, out, cnt);
}

// Round 10
// 17328.517 us; speedup vs baseline: 2.2700x; 1.6333x over previous
//
#include <hip/hip_runtime.h>

// GRU scan: B=32, S=1024, IN=512, H=1024.
// R3 design, resubmit #7 (R3-R9 benches all infra acquisition timeouts — this
// kernel has never run). Identical to R6/R7/R8 submission (gbar watchdog).
//
// Design: 64 WGs x 4 waves (K-split + LDS reduction). Cross-WG data (hb, rhb)
// moves via sc0/sc1 cache-bypassing loads/stores (coherent at MALL) -> no
// agent fences, no per-step L2 writeback/invalidate; L2 stays warm for x.
// z and f32 h never leave the WG (zt/ht in LDS). Grid barrier = vmcnt(0)
// drain + relaxed system-scope atomic + relaxed spin + watchdog (a coherence
// failure degrades to wrong-answer, not a hang).

#define B_   32
#define S_   1024
#define IN_  512
#define H_   1024
#define K_   1536
#define NWG  64

typedef __bf16 bf16;
typedef __bf16 bf16x8 __attribute__((ext_vector_type(8)));
typedef float  f32x16 __attribute__((ext_vector_type(16)));
typedef float  f32x4  __attribute__((ext_vector_type(4)));
typedef unsigned int u32;

// ---------------- ws layout (bytes) ----------------
#define OFF_CNT ((size_t)0)                       // barrier counter (1 KiB)
#define OFF_XB  ((size_t)1024)                    // x bf16: 32 MiB
#define OFF_WZR (OFF_XB  + (size_t)B_*S_*IN_*2)   // [W_z;W_r] bf16: 6 MiB
#define OFF_WH  (OFF_WZR + (size_t)2*H_*K_*2)     // W_h bf16: 3 MiB
#define OFF_HB  (OFF_WH  + (size_t)H_*K_*2)       // h bf16: 64 KiB
#define OFF_RH  (OFF_HB  + (size_t)B_*H_*2)       // (r*h) bf16: 64 KiB

// ---------------- LDS layout (bytes) ----------------
// Weight tiles: col stride 3088 (3072 + 16B pad, 16B-aligned).
#define ST      3088
#define SA_OFF  0                                  // 32 cols (16 z | 16 r): 98816
#define SB_OFF  (32 * ST)                          // 16 Wh cols: 49408
#define RED_OFF (SB_OFF + 16 * ST)                 // 148224: partials, 12288
#define ZT_OFF  (RED_OFF + 6144)                   // z tile 32x16 f32 (2 KiB)
#define HT_OFF  (RED_OFF + 12288)                  // f32 h tile 32x16 (2 KiB)
#define LDS_TOTAL (HT_OFF + 2048)                  // 162560 <= 163840

__global__ void cvt_f32_bf16(const float* __restrict__ src, bf16* __restrict__ dst, int n4) {
  int i = blockIdx.x * blockDim.x + threadIdx.x;
  if (i >= n4) return;
  float4 v = reinterpret_cast<const float4*>(src)[i];
  union { bf16 b[4]; uint2 u; } o;
  o.b[0] = (bf16)v.x; o.b[1] = (bf16)v.y; o.b[2] = (bf16)v.z; o.b[3] = (bf16)v.w;
  reinterpret_cast<uint2*>(dst)[i] = o.u;
}

__global__ void init_hb(const float* __restrict__ ih, bf16* __restrict__ hb) {
  int i = blockIdx.x * blockDim.x + threadIdx.x;   // 0 .. B_*H_-1
  hb[i] = (bf16)ih[i & (H_ - 1)];
}

__device__ inline f32x16 mfma32(bf16x8 a, bf16x8 b, f32x16 c) {
  return __builtin_amdgcn_mfma_f32_32x32x16_bf16(a, b, c, 0, 0, 0);
}
__device__ inline f32x4 mfma16(bf16x8 a, bf16x8 b, f32x4 c) {
  return __builtin_amdgcn_mfma_f32_16x16x32_bf16(a, b, c, 0, 0, 0);
}

__device__ inline void st_short_sys(void* p, u32 v) {
  asm volatile("global_store_short %0, %1, off sc0 sc1" :: "v"(p), "v"(v) : "memory");
}
__device__ inline u32 bf16bits(float f) {
  union { bf16 b; unsigned short us; } u;
  u.b = (bf16)f;
  return (u32)u.us;
}

__device__ inline float sigmoid_f(float x) { return 1.f / (1.f + __expf(-x)); }
__device__ inline float tanh_f(float x) {
  x = fminf(20.f, fmaxf(-20.f, x));
  float e = __expf(-2.f * x);
  return (1.f - e) / (1.f + e);
}

// Grid barrier: wave-0 stores are sc0sc1 (memory-side); drain vmcnt, then
// relaxed system-scope arrive + spin. No cache fences needed. Watchdog turns
// a (model-falsifying) never-observed arrive into wrong results, not a hang.
__device__ inline void gbar(int* cnt, int target) {
  if (threadIdx.x == 0) {
    asm volatile("s_waitcnt vmcnt(0)" ::: "memory");
    __hip_atomic_fetch_add(cnt, 1, __ATOMIC_RELAXED, __HIP_MEMORY_SCOPE_SYSTEM);
    int guard = 0;
    while (__hip_atomic_load(cnt, __ATOMIC_RELAXED, __HIP_MEMORY_SCOPE_SYSTEM) < target) {
      __builtin_amdgcn_s_sleep(1);
      if (++guard > (1 << 17)) break;   // ~5 ms >> ~5 us legit wait
    }
  }
  __syncthreads();
}

__global__ void __launch_bounds__(256, 1) gru_persist(
    const bf16* __restrict__ xb, const bf16* __restrict__ wzr, const bf16* __restrict__ wh,
    const float* __restrict__ bz, const float* __restrict__ br, const float* __restrict__ bh,
    const float* __restrict__ ih,
    bf16* __restrict__ hb, bf16* __restrict__ rhb,
    float* __restrict__ out, int* cnt)
{
  extern __shared__ char smem[];
  const int wg   = blockIdx.x;
  const int tid  = threadIdx.x;
  const int wv   = tid >> 6;        // wave 0..3 (K-split)
  const int lane = tid & 63;
  const int lo   = lane & 31, hi   = lane >> 5;   // 32x32 coords
  const int lo16 = lane & 15, hi16 = lane >> 4;   // 16x16 coords

  // ---- one-time staging ----
  // Phase A tile: cols 0-15 = Wz rows [16wg,16wg+16), cols 16-31 = Wr rows.
  for (int idx = tid; idx < 32 * 192; idx += 256) {
    int c = idx / 192, off = (idx % 192) * 16;
    const char* src = (c < 16)
        ? (const char*)(wzr + (size_t)(16 * wg + c) * K_)
        : (const char*)(wzr + (size_t)(H_ + 16 * wg + (c - 16)) * K_);
    *(bf16x8*)(smem + SA_OFF + (size_t)c * ST + off) = *(const bf16x8*)(src + off);
  }
  for (int idx = tid; idx < 16 * 192; idx += 256) {
    int c = idx / 192, off = (idx % 192) * 16;
    *(bf16x8*)(smem + SB_OFF + (size_t)c * ST + off) =
        *(const bf16x8*)((const char*)(wh + (size_t)(16 * wg + c) * K_) + off);
  }
  for (int idx = tid; idx < 512; idx += 256)       // ht[m][c] = ih (f32 master h)
    *(float*)(smem + HT_OFF + idx * 4) = ih[16 * wg + (idx & 15)];
  __syncthreads();

  // per-lane constants
  const int   nA    = lane & 31;                   // phase A output col (z:0-15, r:16-31)
  const float biasA = (nA < 16) ? bz[16 * wg + nA] : br[16 * wg + (nA - 16)];
  const int   cB    = 16 * wg + lo16;
  const float biasB = bh[cB];
  const float ihv   = ih[cB];
  f32x4 hown0, hown1;
  #pragma unroll
  for (int i = 0; i < 4; ++i) { hown0[i] = ihv; hown1[i] = ihv; }

  // LDS B-operand bases (per-wave K slices)
  const char* bAx = smem + SA_OFF + (size_t)lo * ST + wv * 256 + hi * 16;
  const char* bAh = smem + SA_OFF + (size_t)lo * ST + 1024 + wv * 512 + hi * 16;
  const char* bBx = smem + SB_OFF + (size_t)lo16 * ST + wv * 256 + hi16 * 16;
  const char* bBh = smem + SB_OFF + (size_t)lo16 * ST + 1024 + wv * 512 + hi16 * 16;
  // global sc-load bases
  const char* hbase  = (const char*)hb  + (size_t)lo * 2048 + wv * 512 + hi * 16;
  const char* r0base = (const char*)rhb + (size_t)lo16 * 2048 + wv * 512 + hi16 * 16;
  const char* r1base = r0base + 16 * 2048;

  int bar = 1;
  for (int t = 0; t < S_; ++t) {
    // =================== phase A ===================
    bf16x8 h0,h1,h2,h3,h4,h5,h6,h7,h8,h9,h10,h11,h12,h13,h14,h15;
    asm volatile(
      "global_load_dwordx4 %0, %16, off sc0 sc1\n"
      "global_load_dwordx4 %1, %16, off offset:32 sc0 sc1\n"
      "global_load_dwordx4 %2, %16, off offset:64 sc0 sc1\n"
      "global_load_dwordx4 %3, %16, off offset:96 sc0 sc1\n"
      "global_load_dwordx4 %4, %16, off offset:128 sc0 sc1\n"
      "global_load_dwordx4 %5, %16, off offset:160 sc0 sc1\n"
      "global_load_dwordx4 %6, %16, off offset:192 sc0 sc1\n"
      "global_load_dwordx4 %7, %16, off offset:224 sc0 sc1\n"
      "global_load_dwordx4 %8, %16, off offset:256 sc0 sc1\n"
      "global_load_dwordx4 %9, %16, off offset:288 sc0 sc1\n"
      "global_load_dwordx4 %10, %16, off offset:320 sc0 sc1\n"
      "global_load_dwordx4 %11, %16, off offset:352 sc0 sc1\n"
      "global_load_dwordx4 %12, %16, off offset:384 sc0 sc1\n"
      "global_load_dwordx4 %13, %16, off offset:416 sc0 sc1\n"
      "global_load_dwordx4 %14, %16, off offset:448 sc0 sc1\n"
      "global_load_dwordx4 %15, %16, off offset:480 sc0 sc1"
      : "=v"(h0),"=v"(h1),"=v"(h2),"=v"(h3),"=v"(h4),"=v"(h5),"=v"(h6),"=v"(h7),
        "=v"(h8),"=v"(h9),"=v"(h10),"=v"(h11),"=v"(h12),"=v"(h13),"=v"(h14),"=v"(h15)
      : "v"(hbase) : "memory");

    f32x16 accX, aH0, aH1;
    #pragma unroll
    for (int i = 0; i < 16; ++i) { accX[i] = 0.f; aH0[i] = 0.f; aH1[i] = 0.f; }

    const bf16* pa = xb + ((size_t)lo * S_ + t) * IN_ + wv * 128 + hi * 8;
    #pragma unroll
    for (int kk = 0; kk < 8; ++kk) {                 // x chain overlaps h loads
      bf16x8 av = *(const bf16x8*)(pa + kk * 16);
      bf16x8 bv = *(const bf16x8*)(bAx + kk * 32);
      accX = mfma32(av, bv, accX);
    }
    asm volatile("s_waitcnt vmcnt(0)" ::: "memory");
    __builtin_amdgcn_sched_barrier(0);
    #define MF_A0(J, HV) aH0 = mfma32(HV, *(const bf16x8*)(bAh + (J)*32), aH0);
    #define MF_A1(J, HV) aH1 = mfma32(HV, *(const bf16x8*)(bAh + 256 + (J)*32), aH1);
    MF_A0(0,h0) MF_A0(1,h1) MF_A0(2,h2) MF_A0(3,h3)
    MF_A0(4,h4) MF_A0(5,h5) MF_A0(6,h6) MF_A0(7,h7)
    MF_A1(0,h8) MF_A1(1,h9) MF_A1(2,h10) MF_A1(3,h11)
    MF_A1(4,h12) MF_A1(5,h13) MF_A1(6,h14) MF_A1(7,h15)

    f32x16 acc;
    #pragma unroll
    for (int i = 0; i < 16; ++i) acc[i] = accX[i] + aH0[i] + aH1[i];

    if (wv) {
      #pragma unroll
      for (int rg = 0; rg < 16; ++rg)
        *(float*)(smem + RED_OFF + (size_t)(wv - 1) * 4096 + rg * 256 + lane * 4) = acc[rg];
    }
    __syncthreads();
    if (wv == 0) {
      #pragma unroll
      for (int rg = 0; rg < 16; ++rg) {
        const char* p = smem + RED_OFF + rg * 256 + lane * 4;
        acc[rg] += *(const float*)p + *(const float*)(p + 4096) + *(const float*)(p + 8192);
      }
      if (nA < 16) {                                  // z columns: stay in LDS
        #pragma unroll
        for (int rg = 0; rg < 16; ++rg) {
          int m = (rg & 3) + 8 * (rg >> 2) + 4 * hi;
          *(float*)(smem + ZT_OFF + m * 64 + nA * 4) = sigmoid_f(acc[rg] + biasA);
        }
      } else {                                        // r columns: store r*h (bf16, sc)
        int c = nA - 16;
        char* rbase = (char*)rhb + (size_t)(16 * wg + c) * 2;
        #pragma unroll
        for (int rg = 0; rg < 16; ++rg) {
          int m = (rg & 3) + 8 * (rg >> 2) + 4 * hi;
          float rv = sigmoid_f(acc[rg] + biasA);
          float hv = *(const float*)(smem + HT_OFF + m * 64 + c * 4);
          st_short_sys(rbase + (size_t)m * 2048, bf16bits(rv * hv));
        }
      }
    }
    gbar(cnt, (bar++) * NWG);

    // =================== phase B ===================
    bf16x8 r00,r01,r02,r03,r04,r05,r06,r07,r10,r11,r12,r13,r14,r15,r16,r17;
    asm volatile(
      "global_load_dwordx4 %0, %16, off sc0 sc1\n"
      "global_load_dwordx4 %1, %16, off offset:64 sc0 sc1\n"
      "global_load_dwordx4 %2, %16, off offset:128 sc0 sc1\n"
      "global_load_dwordx4 %3, %16, off offset:192 sc0 sc1\n"
      "global_load_dwordx4 %4, %16, off offset:256 sc0 sc1\n"
      "global_load_dwordx4 %5, %16, off offset:320 sc0 sc1\n"
      "global_load_dwordx4 %6, %16, off offset:384 sc0 sc1\n"
      "global_load_dwordx4 %7, %16, off offset:448 sc0 sc1\n"
      "global_load_dwordx4 %8, %17, off sc0 sc1\n"
      "global_load_dwordx4 %9, %17, off offset:64 sc0 sc1\n"
      "global_load_dwordx4 %10, %17, off offset:128 sc0 sc1\n"
      "global_load_dwordx4 %11, %17, off offset:192 sc0 sc1\n"
      "global_load_dwordx4 %12, %17, off offset:256 sc0 sc1\n"
      "global_load_dwordx4 %13, %17, off offset:320 sc0 sc1\n"
      "global_load_dwordx4 %14, %17, off offset:384 sc0 sc1\n"
      "global_load_dwordx4 %15, %17, off offset:448 sc0 sc1"
      : "=v"(r00),"=v"(r01),"=v"(r02),"=v"(r03),"=v"(r04),"=v"(r05),"=v"(r06),"=v"(r07),
        "=v"(r10),"=v"(r11),"=v"(r12),"=v"(r13),"=v"(r14),"=v"(r15),"=v"(r16),"=v"(r17)
      : "v"(r0base), "v"(r1base) : "memory");

    f32x4 a0x, a1x, a0h, a1h;
    #pragma unroll
    for (int i = 0; i < 4; ++i) { a0x[i] = 0.f; a1x[i] = 0.f; a0h[i] = 0.f; a1h[i] = 0.f; }

    const bf16* pb0 = xb + ((size_t)lo16 * S_ + t) * IN_ + wv * 128 + hi16 * 8;
    const bf16* pb1 = pb0 + (size_t)16 * S_ * IN_;
    #pragma unroll
    for (int kk = 0; kk < 4; ++kk) {
      bf16x8 bv = *(const bf16x8*)(bBx + kk * 64);
      a0x = mfma16(*(const bf16x8*)(pb0 + kk * 32), bv, a0x);
      a1x = mfma16(*(const bf16x8*)(pb1 + kk * 32), bv, a1x);
    }
    asm volatile("s_waitcnt vmcnt(0)" ::: "memory");
    __builtin_amdgcn_sched_barrier(0);
    #define MF_B(J, RV0, RV1) { bf16x8 bv = *(const bf16x8*)(bBh + (J)*64); \
        a0h = mfma16(RV0, bv, a0h); a1h = mfma16(RV1, bv, a1h); }
    MF_B(0,r00,r10) MF_B(1,r01,r11) MF_B(2,r02,r12) MF_B(3,r03,r13)
    MF_B(4,r04,r14) MF_B(5,r05,r15) MF_B(6,r06,r16) MF_B(7,r07,r17)

    if (wv) {
      #pragma unroll
      for (int rg = 0; rg < 4; ++rg) {
        *(float*)(smem + RED_OFF + (size_t)(wv - 1) * 2048 + rg * 256 + lane * 4) = a0x[rg] + a0h[rg];
        *(float*)(smem + RED_OFF + (size_t)(wv - 1) * 2048 + 1024 + rg * 256 + lane * 4) = a1x[rg] + a1h[rg];
      }
    }
    __syncthreads();
    if (wv == 0) {
      char* hbst = (char*)hb + (size_t)cB * 2;
      #pragma unroll
      for (int rg = 0; rg < 4; ++rg) {
        const char* p = smem + RED_OFF + rg * 256 + lane * 4;
        float s0 = a0x[rg] + a0h[rg] + *(const float*)p + *(const float*)(p + 2048) + *(const float*)(p + 4096);
        const char* q = p + 1024;
        float s1 = a1x[rg] + a1h[rg] + *(const float*)q + *(const float*)(q + 2048) + *(const float*)(q + 4096);
        int m0 = hi16 * 4 + rg, m1 = m0 + 16;

        float hh0 = tanh_f(s0 + biasB);
        float z0  = *(const float*)(smem + ZT_OFF + m0 * 64 + lo16 * 4);
        float hn0 = hown0[rg] + z0 * (hh0 - hown0[rg]);
        hown0[rg] = hn0;
        *(float*)(smem + HT_OFF + m0 * 64 + lo16 * 4) = hn0;
        st_short_sys(hbst + (size_t)m0 * 2048, bf16bits(hn0));
        out[((size_t)m0 * S_ + t) * H_ + cB] = hn0;

        float hh1 = tanh_f(s1 + biasB);
        float z1  = *(const float*)(smem + ZT_OFF + m1 * 64 + lo16 * 4);
        float hn1 = hown1[rg] + z1 * (hh1 - hown1[rg]);
        hown1[rg] = hn1;
        *(float*)(smem + HT_OFF + m1 * 64 + lo16 * 4) = hn1;
        st_short_sys(hbst + (size_t)m1 * 2048, bf16bits(hn1));
        out[((size_t)m1 * S_ + t) * H_ + cB] = hn1;
      }
      if (t == S_ - 1) {
        #pragma unroll
        for (int rg = 0; rg < 4; ++rg) {
          int m0 = hi16 * 4 + rg, m1 = m0 + 16;
          out[(size_t)B_ * S_ * H_ + (size_t)m0 * H_ + cB] = hown0[rg];
          out[(size_t)B_ * S_ * H_ + (size_t)m1 * H_ + cB] = hown1[rg];
        }
      }
    }
    if (t + 1 < S_) { gbar(cnt, (bar++) * NWG); }
  }
}

extern "C" void kernel_launch(void* const* d_in, const int* in_sizes, int n_in,
                              void* d_out, int out_size, void* d_ws, size_t ws_size,
                              hipStream_t stream) {
  (void)in_sizes; (void)n_in; (void)out_size; (void)ws_size;
  const float* x  = (const float*)d_in[0];
  const float* Wz = (const float*)d_in[1];
  const float* bz = (const float*)d_in[2];
  const float* Wr = (const float*)d_in[3];
  const float* br = (const float*)d_in[4];
  const float* Wh = (const float*)d_in[5];
  const float* bh = (const float*)d_in[6];
  const float* ih = (const float*)d_in[7];
  float* out = (float*)d_out;
  char*  ws  = (char*)d_ws;

  bf16* xb  = (bf16*)(ws + OFF_XB);
  bf16* wzr = (bf16*)(ws + OFF_WZR);
  bf16* wh  = (bf16*)(ws + OFF_WH);
  bf16* hb  = (bf16*)(ws + OFF_HB);
  bf16* rhb = (bf16*)(ws + OFF_RH);
  int*  cnt = (int*)(ws + OFF_CNT);

  hipFuncSetAttribute(reinterpret_cast<const void*>(&gru_persist),
                      hipFuncAttributeMaxDynamicSharedMemorySize, LDS_TOTAL);

  hipMemsetAsync(ws + OFF_CNT, 0, 1024, stream);

  const int n4x = B_ * S_ * IN_ / 4;
  cvt_f32_bf16<<<n4x / 256, 256, 0, stream>>>(x, xb, n4x);
  const int n4w = H_ * K_ / 4;
  cvt_f32_bf16<<<n4w / 256, 256, 0, stream>>>(Wz, wzr, n4w);
  cvt_f32_bf16<<<n4w / 256, 256, 0, stream>>>(Wr, wzr + (size_t)H_ * K_, n4w);
  cvt_f32_bf16<<<n4w / 256, 256, 0, stream>>>(Wh, wh, n4w);
  init_hb<<<(B_ * H_) / 256, 256, 0, stream>>>(ih, hb);

  gru_persist<<<NWG, 256, LDS_TOTAL, stream>>>(xb, wzr, wh, bz, br, bh, ih,
                                               hb, rhb, out, cnt);
}